// Round 4
// baseline (227.607 us; speedup 1.0000x reference)
//
#include <hip/hip_runtime.h>
#include <hip/hip_fp16.h>
#include <math.h>

// FourierKNOConv2d: x[8,32,256,256] f32, kernel[2,1,32,32,32,2] f32, r scalar.
// Pipeline (fp32 compute, fp16 data-at-rest, Chebyshev twiddle recurrences):
//   kP: Kp = (kr+i ki)^r                      fp32 [2,32,32,32]
//   kA: Z1[row,w] = sum_x X e^{-iθwx}  (u/v x-symmetry, 127 iters)   -> fp16
//   kB: Z2q[t,w] partial over 64 y      (4 y-quarters)               -> fp16
//   kC: G = idft32_ch(dft32_ch(sum_q Z2q) * Kp)/8192                 -> fp16
//   kDE: T[y,w] = sum_t G e^{+iθh(t)y} (LDS) then out via x-symmetry -> f32
// ws: z1h 8MB@0, z2p 8MB@8M, g 2MB@16M, kp 0.5MB@18M.

#define TWO_PI 6.28318530717958647692f
#define W256 0.0245436926061702596f  // 2*pi/256

struct alignas(8) H4 { __half2 a, b; };
struct alignas(16) H8 { __half2 a, b, c, d; };

__global__ __launch_bounds__(256) void kP(const float* __restrict__ kin,
                                          const float* __restrict__ rp,
                                          float2* __restrict__ kp) {
  const int i = blockIdx.x * 256 + threadIdx.x;  // < 65536
  const float r = rp[0];
  const float kr = kin[2 * i], ki = kin[2 * i + 1];
  const float m2 = fmaf(kr, kr, ki * ki);
  float2 o = make_float2(0.f, 0.f);
  if (m2 > 0.f) {
    const float lm = 0.5f * logf(m2);
    const float ang = atan2f(ki, kr);
    const float mag = expf(r * lm);
    float s, c;
    sincosf(r * ang, &s, &c);
    o = make_float2(mag * c, mag * s);
  }
  kp[i] = o;
}

// kA: 1024 blocks x 128 thr; block = 64 rows. LDS fp16 [x][64 r] stride 68.
// Thread = (rg=tid&15 -> 4 rows, wg=tid>>4 -> 4 w). Cheb chains over x per w.
__global__ __launch_bounds__(128) void kA(const float* __restrict__ x,
                                          H8* __restrict__ z1h) {
  __shared__ __half xs[256 * 68];  // 34 KB
  const int tid = threadIdx.x;
  const long row0 = (long)blockIdx.x * 64;
  const float* xg = x + row0 * 256;
  // stage transposed fp16: 8 sweeps of (4 rows x 4 x) per thread
  {
    const int xsl = tid & 15, rg8 = tid >> 4;
#pragma unroll
    for (int sw = 0; sw < 8; ++sw) {
      const int sx = sw & 3, sr = sw >> 2;
      const int x0 = (xsl + sx * 16) * 4;
      const int r0 = rg8 * 4 + sr * 32;
      float4 f0 = *(const float4*)&xg[(r0 + 0) * 256 + x0];
      float4 f1 = *(const float4*)&xg[(r0 + 1) * 256 + x0];
      float4 f2 = *(const float4*)&xg[(r0 + 2) * 256 + x0];
      float4 f3 = *(const float4*)&xg[(r0 + 3) * 256 + x0];
      const float* p0 = (const float*)&f0;
      const float* p1 = (const float*)&f1;
      const float* p2 = (const float*)&f2;
      const float* p3 = (const float*)&f3;
#pragma unroll
      for (int c = 0; c < 4; ++c) {
        H4 h;
        h.a = __floats2half2_rn(p0[c], p1[c]);
        h.b = __floats2half2_rn(p2[c], p3[c]);
        *(H4*)&xs[(x0 + c) * 68 + r0] = h;
      }
    }
  }
  __syncthreads();
  // u/v pairing: slot x <- a+b, slot 256-x <- a-b (x=1..127); slots 0,128 raw
  for (int i = tid; i < 2032; i += 128) {
    const int xi = 1 + (i >> 4), rq = (i & 15) * 4;
    H4 a = *(const H4*)&xs[xi * 68 + rq];
    H4 b = *(const H4*)&xs[(256 - xi) * 68 + rq];
    H4 u, v;
    u.a = __hadd2(a.a, b.a); u.b = __hadd2(a.b, b.b);
    v.a = __hsub2(a.a, b.a); v.b = __hsub2(a.b, b.b);
    *(H4*)&xs[xi * 68 + rq] = u;
    *(H4*)&xs[(256 - xi) * 68 + rq] = v;
  }
  __syncthreads();
  const int r0 = (tid & 15) * 4;
  const int w0 = (tid >> 4) * 4;
  // chains: c_i = cos(w*x*W256) etc, consume x=1 first
  float ci_[4], si_[4], cp_[4], sp_[4], kk[4];
#pragma unroll
  for (int j = 0; j < 4; ++j) {
    float s, c;
    sincosf(W256 * (float)(w0 + j), &s, &c);
    kk[j] = 2.f * c;
    cp_[j] = 1.f; sp_[j] = 0.f;
    ci_[j] = c;  si_[j] = s;
  }
  float Cr[4][4], Ci[4][4];
  {  // edge terms: Re += X0 + (-1)^w X128  (w0 even -> sign = (-1)^j)
    H4 h0 = *(const H4*)&xs[r0];
    H4 h128 = *(const H4*)&xs[128 * 68 + r0];
    float x0f[4] = {__half2float(h0.a.x), __half2float(h0.a.y),
                    __half2float(h0.b.x), __half2float(h0.b.y)};
    float x1f[4] = {__half2float(h128.a.x), __half2float(h128.a.y),
                    __half2float(h128.b.x), __half2float(h128.b.y)};
#pragma unroll
    for (int j = 0; j < 4; ++j) {
      const float sg = (j & 1) ? -1.f : 1.f;
#pragma unroll
      for (int i = 0; i < 4; ++i) {
        Cr[j][i] = fmaf(sg, x1f[i], x0f[i]);
        Ci[j][i] = 0.f;
      }
    }
  }
  for (int xx = 1; xx < 128; ++xx) {
    H4 u = *(const H4*)&xs[xx * 68 + r0];
    H4 v = *(const H4*)&xs[(256 - xx) * 68 + r0];
    const float uf[4] = {__half2float(u.a.x), __half2float(u.a.y),
                         __half2float(u.b.x), __half2float(u.b.y)};
    const float vf[4] = {__half2float(v.a.x), __half2float(v.a.y),
                         __half2float(v.b.x), __half2float(v.b.y)};
#pragma unroll
    for (int j = 0; j < 4; ++j) {
      const float c = ci_[j], s = si_[j];
#pragma unroll
      for (int i = 0; i < 4; ++i) {
        Cr[j][i] = fmaf(uf[i], c, Cr[j][i]);
        Ci[j][i] = fmaf(-vf[i], s, Ci[j][i]);
      }
      const float cn = fmaf(kk[j], c, -cp_[j]);
      const float sn = fmaf(kk[j], s, -sp_[j]);
      cp_[j] = c; ci_[j] = cn;
      sp_[j] = s; si_[j] = sn;
    }
  }
#pragma unroll
  for (int i = 0; i < 4; ++i) {
    H8 o;
    o.a = __floats2half2_rn(Cr[0][i], Ci[0][i]);
    o.b = __floats2half2_rn(Cr[1][i], Ci[1][i]);
    o.c = __floats2half2_rn(Cr[2][i], Ci[2][i]);
    o.d = __floats2half2_rn(Cr[3][i], Ci[3][i]);
    z1h[(row0 + r0 + i) * 8 + (w0 >> 2)] = o;
  }
}

// kB: 1024 blocks = (bc, yq of 64 y) x 128 thr. Thread = (tg=tid&15 -> 4 t,
// wg=tid>>4 -> 4 w). Partial Z2 over 64 y -> z2p[yq]. Cheb chains over y per t.
__global__ __launch_bounds__(128) void kB(const H8* __restrict__ z1h,
                                          H8* __restrict__ z2p) {
  __shared__ __half zs[64 * 64];  // [y][w re/im], 8 KB
  const int bc = blockIdx.x >> 2, yq = blockIdx.x & 3;
  const int y0 = yq * 64;
  {
    const int4* src = (const int4*)(z1h + ((long)bc * 256 + y0) * 8);
    int4* dst = (int4*)zs;
    for (int i = threadIdx.x; i < 512; i += 128) dst[i] = src[i];
  }
  __syncthreads();
  const int t0 = (threadIdx.x & 15) * 4;
  const int w0 = (threadIdx.x >> 4) * 4;
  float ci_[4], si_[4], cp_[4], sp_[4], kk[4];
#pragma unroll
  for (int k = 0; k < 4; ++k) {
    const int t = t0 + k;
    const int h = (t < 32) ? t : (192 + t);
    const int m0 = (h * y0) & 255;
    const int mp = (h * (y0 + 255)) & 255;  // == h*(y0-1) mod 256
    float s0, c0, sp1, cp1;
    sincosf(W256 * (float)m0, &s0, &c0);
    sincosf(W256 * (float)mp, &sp1, &cp1);
    ci_[k] = c0;  si_[k] = -s0;   // phase = -2pi h y/256
    cp_[k] = cp1; sp_[k] = -sp1;
    kk[k] = 2.f * cosf(W256 * (float)h);
  }
  float ar[4][4], ai[4][4];
#pragma unroll
  for (int k = 0; k < 4; ++k)
#pragma unroll
    for (int i = 0; i < 4; ++i) { ar[k][i] = 0.f; ai[k][i] = 0.f; }
  for (int y = 0; y < 64; ++y) {
    H8 z = *(const H8*)&zs[y * 64 + w0 * 2];
    const float zr[4] = {__half2float(z.a.x), __half2float(z.b.x),
                         __half2float(z.c.x), __half2float(z.d.x)};
    const float zi[4] = {__half2float(z.a.y), __half2float(z.b.y),
                         __half2float(z.c.y), __half2float(z.d.y)};
#pragma unroll
    for (int k = 0; k < 4; ++k) {
      const float c = ci_[k], s = si_[k];
#pragma unroll
      for (int i = 0; i < 4; ++i) {
        ar[k][i] = fmaf(zr[i], c, fmaf(-zi[i], s, ar[k][i]));
        ai[k][i] = fmaf(zr[i], s, fmaf(zi[i], c, ai[k][i]));
      }
      const float cn = fmaf(kk[k], c, -cp_[k]);
      const float sn = fmaf(kk[k], s, -sp_[k]);
      cp_[k] = c; ci_[k] = cn;
      sp_[k] = s; si_[k] = sn;
    }
  }
#pragma unroll
  for (int k = 0; k < 4; ++k) {
    H8 o;
    o.a = __floats2half2_rn(ar[k][0], ai[k][0]);
    o.b = __floats2half2_rn(ar[k][1], ai[k][1]);
    o.c = __floats2half2_rn(ar[k][2], ai[k][2]);
    o.d = __floats2half2_rn(ar[k][3], ai[k][3]);
    z2p[(((long)yq * 256 + bc) * 64 + t0 + k) * 8 + (w0 >> 2)] = o;
  }
}

// kC: 1024 blocks x 256 thr; block = 16 modes (same b,t; 16 w). Sums 4 partials.
__global__ __launch_bounds__(256) void kC(const __half2* __restrict__ z2p,
                                          const float2* __restrict__ kp,
                                          __half2* __restrict__ g) {
  __shared__ float2 z2s[16 * 33];
  __shared__ float2 fk[16 * 33];
  __shared__ float2 tw[32];
  const int tid = threadIdx.x;
  if (tid < 32) {
    float s, c;
    sincosf(-TWO_PI * (float)tid / 32.0f, &s, &c);
    tw[tid] = make_float2(c, s);
  }
  const int m0 = blockIdx.x * 16;
  const int b = m0 >> 11;
  const int twi = m0 & 2047;
  const int t = twi >> 5;
  const int w0 = twi & 31;  // 0 or 16
  const int s_ = t >> 5, tm = t & 31;
  for (int i = tid; i < 512; i += 256) {
    const int ci = i >> 4, wj = i & 15;
    const long idx = ((long)(b * 32 + ci)) * 2048 + t * 32 + w0 + wj;
    float sr = 0.f, si = 0.f;
#pragma unroll
    for (int q = 0; q < 4; ++q) {
      const __half2 v = z2p[(long)q * 524288 + idx];
      sr += __half2float(v.x);
      si += __half2float(v.y);
    }
    z2s[wj * 33 + ci] = make_float2(sr, si);
  }
  __syncthreads();
  const int m = tid & 15;
  const int p = tid >> 4;
  const int cf0 = 2 * p, cf1 = 2 * p + 1;
  {
    float f0r = 0, f0i = 0, f1r = 0, f1i = 0;
    int i0 = 0, i1 = 0;
#pragma unroll 8
    for (int ci = 0; ci < 32; ++ci) {
      const float2 z = z2s[m * 33 + ci];
      const float2 t0 = tw[i0]; i0 = (i0 + cf0) & 31;
      const float2 t1 = tw[i1]; i1 = (i1 + cf1) & 31;
      f0r = fmaf(z.x, t0.x, fmaf(-z.y, t0.y, f0r));
      f0i = fmaf(z.x, t0.y, fmaf(z.y, t0.x, f0i));
      f1r = fmaf(z.x, t1.x, fmaf(-z.y, t1.y, f1r));
      f1i = fmaf(z.x, t1.y, fmaf(z.y, t1.x, f1i));
    }
    const float2 k0 = kp[((s_ * 32 + cf0) * 32 + tm) * 32 + w0 + m];
    const float2 k1 = kp[((s_ * 32 + cf1) * 32 + tm) * 32 + w0 + m];
    fk[m * 33 + cf0] = make_float2(f0r * k0.x - f0i * k0.y, f0r * k0.y + f0i * k0.x);
    fk[m * 33 + cf1] = make_float2(f1r * k1.x - f1i * k1.y, f1r * k1.y + f1i * k1.x);
  }
  __syncthreads();
  {
    float g0r = 0, g0i = 0, g1r = 0, g1i = 0;
    int i0 = 0, i1 = 0;
    const int co0 = 2 * p, co1 = 2 * p + 1;
#pragma unroll 8
    for (int cf = 0; cf < 32; ++cf) {
      const float2 f = fk[m * 33 + cf];
      const float2 t0 = tw[i0]; i0 = (i0 + co0) & 31;
      const float2 t1 = tw[i1]; i1 = (i1 + co1) & 31;
      g0r = fmaf(f.x, t0.x, fmaf(f.y, t0.y, g0r));
      g0i = fmaf(f.y, t0.x, fmaf(-f.x, t0.y, g0i));
      g1r = fmaf(f.x, t1.x, fmaf(f.y, t1.y, g1r));
      g1i = fmaf(f.y, t1.x, fmaf(-f.x, t1.y, g1i));
    }
    const float SC = 1.0f / 8192.0f;
    g[((long)(b * 32 + co0)) * 2048 + t * 32 + w0 + m] =
        __floats2half2_rn(g0r * SC, g0i * SC);
    g[((long)(b * 32 + co1)) * 2048 + t * 32 + w0 + m] =
        __floats2half2_rn(g1r * SC, g1i * SC);
  }
}

// kDE: 1024 blocks = (bc, yc of 64 y) x 256 thr. Phase D: T[64y x 32w] -> LDS
// (scaled, [w][y] stride 65). Phase E: out via x<->256-x symmetry.
__global__ __launch_bounds__(256) void kDE(const __half2* __restrict__ g,
                                           float* __restrict__ out) {
  __shared__ __half2 gs[2048];      // [t][w], 8 KB
  __shared__ float2 Tst[32 * 65];   // [w][y], 16.6 KB
  const int tid = threadIdx.x;
  const int bc = blockIdx.x >> 2, yc = blockIdx.x & 3;
  const int y0 = yc * 64;
  {
    const int4* src = (const int4*)(g + (long)bc * 2048);
    int4* dst = (int4*)gs;
    for (int i = tid; i < 512; i += 256) dst[i] = src[i];
  }
  __syncthreads();
  // Phase D: thread = (wg=tid&7 -> 4 w, yg=tid>>3 -> 2 y)
  {
    const int w0 = (tid & 7) * 4;
    const int yg = tid >> 3;
    float ci_[2], si_[2], cp_[2], sp_[2], kk[2];
    float Tr[2][4], Ti[2][4];
#pragma unroll
    for (int l = 0; l < 2; ++l) {
      const int y = y0 + yg * 2 + l;
      float sy, cy;
      sincosf(W256 * (float)y, &sy, &cy);
      kk[l] = 2.f * cy;
      ci_[l] = 1.f; si_[l] = 0.f;      // t=0: phase 0
      cp_[l] = cy;  sp_[l] = -sy;      // t=-1: phase -y*W
#pragma unroll
      for (int j = 0; j < 4; ++j) { Tr[l][j] = 0.f; Ti[l][j] = 0.f; }
    }
    for (int t = 0; t < 32; ++t) {
      H8 gz = *(const H8*)&gs[t * 32 + w0];
      const float gr[4] = {__half2float(gz.a.x), __half2float(gz.b.x),
                           __half2float(gz.c.x), __half2float(gz.d.x)};
      const float gi[4] = {__half2float(gz.a.y), __half2float(gz.b.y),
                           __half2float(gz.c.y), __half2float(gz.d.y)};
#pragma unroll
      for (int l = 0; l < 2; ++l) {
        const float c = ci_[l], s = si_[l];
#pragma unroll
        for (int j = 0; j < 4; ++j) {
          Tr[l][j] = fmaf(gr[j], c, fmaf(-gi[j], s, Tr[l][j]));
          Ti[l][j] = fmaf(gr[j], s, fmaf(gi[j], c, Ti[l][j]));
        }
        const float cn = fmaf(kk[l], c, -cp_[l]);
        const float sn = fmaf(kk[l], s, -sp_[l]);
        cp_[l] = c; ci_[l] = cn;
        sp_[l] = s; si_[l] = sn;
      }
    }
#pragma unroll
    for (int l = 0; l < 2; ++l) {  // re-init for t=32: h = 224..255
      const int y = y0 + yg * 2 + l;
      const int m32 = (224 * y) & 255, m31 = (223 * y) & 255;
      float s32, c32, s31, c31;
      sincosf(W256 * (float)m32, &s32, &c32);
      sincosf(W256 * (float)m31, &s31, &c31);
      ci_[l] = c32; si_[l] = s32;
      cp_[l] = c31; sp_[l] = s31;
    }
    for (int t = 32; t < 64; ++t) {
      H8 gz = *(const H8*)&gs[t * 32 + w0];
      const float gr[4] = {__half2float(gz.a.x), __half2float(gz.b.x),
                           __half2float(gz.c.x), __half2float(gz.d.x)};
      const float gi[4] = {__half2float(gz.a.y), __half2float(gz.b.y),
                           __half2float(gz.c.y), __half2float(gz.d.y)};
#pragma unroll
      for (int l = 0; l < 2; ++l) {
        const float c = ci_[l], s = si_[l];
#pragma unroll
        for (int j = 0; j < 4; ++j) {
          Tr[l][j] = fmaf(gr[j], c, fmaf(-gi[j], s, Tr[l][j]));
          Ti[l][j] = fmaf(gr[j], s, fmaf(gi[j], c, Ti[l][j]));
        }
        const float cn = fmaf(kk[l], c, -cp_[l]);
        const float sn = fmaf(kk[l], s, -sp_[l]);
        cp_[l] = c; ci_[l] = cn;
        sp_[l] = s; si_[l] = sn;
      }
    }
#pragma unroll
    for (int l = 0; l < 2; ++l) {
      const int yl = yg * 2 + l;
#pragma unroll
      for (int j = 0; j < 4; ++j) {
        const float sc = (w0 + j == 0) ? (1.0f / 256.0f) : (2.0f / 256.0f);
        Tst[(w0 + j) * 65 + yl] = make_float2(Tr[l][j] * sc, Ti[l][j] * sc);
      }
    }
  }
  __syncthreads();
  // Phase E: thread = (xg=tid&15 -> x=8xg..8xg+7, rh=tid>>4 -> rows rh+16k)
  {
    const int xg = tid & 15, rh = tid >> 4;
    const int x0 = xg * 8;
    float ci_[8], si_[8], cp_[8], sp_[8], kk[8];
#pragma unroll
    for (int j = 0; j < 8; ++j) {
      float sx, cx;
      sincosf(W256 * (float)(x0 + j), &sx, &cx);
      kk[j] = 2.f * cx;
      ci_[j] = 1.f; si_[j] = 0.f;   // w=0
      cp_[j] = cx;  sp_[j] = -sx;   // w=-1
    }
    float C[4][8], S[4][8];
#pragma unroll
    for (int k = 0; k < 4; ++k)
#pragma unroll
      for (int j = 0; j < 8; ++j) { C[k][j] = 0.f; S[k][j] = 0.f; }
    for (int w = 0; w < 32; ++w) {
      float2 tv[4];
#pragma unroll
      for (int k = 0; k < 4; ++k) tv[k] = Tst[w * 65 + rh + 16 * k];
#pragma unroll
      for (int j = 0; j < 8; ++j) {
        const float c = ci_[j], s = si_[j];
#pragma unroll
        for (int k = 0; k < 4; ++k) {
          C[k][j] = fmaf(tv[k].x, c, C[k][j]);
          S[k][j] = fmaf(tv[k].y, s, S[k][j]);
        }
        const float cn = fmaf(kk[j], c, -cp_[j]);
        const float sn = fmaf(kk[j], s, -sp_[j]);
        cp_[j] = c; ci_[j] = cn;
        sp_[j] = s; si_[j] = sn;
      }
    }
    const long rowg0 = (long)bc * 256 + y0;
#pragma unroll
    for (int k = 0; k < 4; ++k) {
      float* base = out + (rowg0 + rh + 16 * k) * 256;
      float4 d0 = make_float4(C[k][0] - S[k][0], C[k][1] - S[k][1],
                              C[k][2] - S[k][2], C[k][3] - S[k][3]);
      float4 d1 = make_float4(C[k][4] - S[k][4], C[k][5] - S[k][5],
                              C[k][6] - S[k][6], C[k][7] - S[k][7]);
      *(float4*)(base + x0) = d0;
      *(float4*)(base + x0 + 4) = d1;
#pragma unroll
      for (int j = 0; j < 8; ++j)  // mirror: x=0 rewrites slot 0 (S[0]=0, same value)
        base[(256 - (x0 + j)) & 255] = C[k][j] + S[k][j];
    }
  }
  // column x=128: sum (-1)^w Ta  (Tst already scaled)
  if (tid < 64) {
    float se = 0.f, so = 0.f;
#pragma unroll
    for (int k = 0; k < 16; ++k) {
      se += Tst[(2 * k) * 65 + tid].x;
      so += Tst[(2 * k + 1) * 65 + tid].x;
    }
    out[((long)bc * 256 + y0 + tid) * 256 + 128] = se - so;
  }
}

extern "C" void kernel_launch(void* const* d_in, const int* in_sizes, int n_in,
                              void* d_out, int out_size, void* d_ws, size_t ws_size,
                              hipStream_t stream) {
  const float* x = (const float*)d_in[0];
  const float* kin = (const float*)d_in[1];
  const float* rp = (const float*)d_in[2];
  float* out = (float*)d_out;
  char* ws = (char*)d_ws;

  H8* z1h = (H8*)(ws);                            // 8 MB: [row][wg] fp16
  H8* z2p = (H8*)(ws + (8ull << 20));             // 8 MB: [yq][bc][t][wg] fp16
  __half2* g = (__half2*)(ws + (16ull << 20));    // 2 MB: [bc][t][w] fp16
  float2* kp = (float2*)(ws + (18ull << 20));     // 0.5 MB

  kP<<<256, 256, 0, stream>>>(kin, rp, kp);
  kA<<<1024, 128, 0, stream>>>(x, z1h);
  kB<<<1024, 128, 0, stream>>>(z1h, z2p);
  kC<<<1024, 256, 0, stream>>>((const __half2*)z2p, kp, g);
  kDE<<<1024, 256, 0, stream>>>(g, out);
}

// Round 5
// 218.552 us; speedup vs baseline: 1.0414x; 1.0414x over previous
//
#include <hip/hip_runtime.h>
#include <hip/hip_fp16.h>
#include <math.h>

// FourierKNOConv2d: x[8,32,256,256] f32, kernel[2,1,32,32,32,2] f32, r scalar.
// Pipeline (fp32 compute, fp16 data-at-rest, Chebyshev twiddle recurrences):
//   kP: Kp = (kr+i ki)^r                      fp32 [2,32,32,32]
//   kA: Z1[row,w] = sum_x X e^{-iθwx}  (u/v x-symmetry, 127 iters)   -> fp16
//   kB: Z2q[t,w] partial over 64 y      (4 y-quarters)               -> fp16
//   kC: G = idft32_ch(dft32_ch(sum_q Z2q) * Kp)/8192                 -> fp16
//   kDE: T[y,w] = sum_t G e^{+iθh(t)y} (LDS) then out via x-symmetry -> f32
//        (32-y slab per block; small register tiles for occupancy)
// ws: z1h 8MB@0, z2p 8MB@8M, g 2MB@16M, kp 0.5MB@18M.

#define TWO_PI 6.28318530717958647692f
#define W256 0.0245436926061702596f  // 2*pi/256

struct alignas(8) H4 { __half2 a, b; };
struct alignas(16) H8 { __half2 a, b, c, d; };

__global__ __launch_bounds__(256) void kP(const float* __restrict__ kin,
                                          const float* __restrict__ rp,
                                          float2* __restrict__ kp) {
  const int i = blockIdx.x * 256 + threadIdx.x;  // < 65536
  const float r = rp[0];
  const float kr = kin[2 * i], ki = kin[2 * i + 1];
  const float m2 = fmaf(kr, kr, ki * ki);
  float2 o = make_float2(0.f, 0.f);
  if (m2 > 0.f) {
    const float lm = 0.5f * logf(m2);
    const float ang = atan2f(ki, kr);
    const float mag = expf(r * lm);
    float s, c;
    sincosf(r * ang, &s, &c);
    o = make_float2(mag * c, mag * s);
  }
  kp[i] = o;
}

// kA: 1024 blocks x 128 thr; block = 64 rows. LDS fp16 [x][64 r] stride 68.
// Thread = (rg=tid&15 -> 4 rows, wg=tid>>4 -> 4 w). Cheb chains over x per w.
__global__ __launch_bounds__(128) void kA(const float* __restrict__ x,
                                          H8* __restrict__ z1h) {
  __shared__ __half xs[256 * 68];  // 34 KB
  const int tid = threadIdx.x;
  const long row0 = (long)blockIdx.x * 64;
  const float* xg = x + row0 * 256;
  // stage transposed fp16: 8 sweeps of (4 rows x 4 x) per thread
  {
    const int xsl = tid & 15, rg8 = tid >> 4;
#pragma unroll
    for (int sw = 0; sw < 8; ++sw) {
      const int sx = sw & 3, sr = sw >> 2;
      const int x0 = (xsl + sx * 16) * 4;
      const int r0 = rg8 * 4 + sr * 32;
      float4 f0 = *(const float4*)&xg[(r0 + 0) * 256 + x0];
      float4 f1 = *(const float4*)&xg[(r0 + 1) * 256 + x0];
      float4 f2 = *(const float4*)&xg[(r0 + 2) * 256 + x0];
      float4 f3 = *(const float4*)&xg[(r0 + 3) * 256 + x0];
      const float* p0 = (const float*)&f0;
      const float* p1 = (const float*)&f1;
      const float* p2 = (const float*)&f2;
      const float* p3 = (const float*)&f3;
#pragma unroll
      for (int c = 0; c < 4; ++c) {
        H4 h;
        h.a = __floats2half2_rn(p0[c], p1[c]);
        h.b = __floats2half2_rn(p2[c], p3[c]);
        *(H4*)&xs[(x0 + c) * 68 + r0] = h;
      }
    }
  }
  __syncthreads();
  // u/v pairing: slot x <- a+b, slot 256-x <- a-b (x=1..127); slots 0,128 raw
  for (int i = tid; i < 2032; i += 128) {
    const int xi = 1 + (i >> 4), rq = (i & 15) * 4;
    H4 a = *(const H4*)&xs[xi * 68 + rq];
    H4 b = *(const H4*)&xs[(256 - xi) * 68 + rq];
    H4 u, v;
    u.a = __hadd2(a.a, b.a); u.b = __hadd2(a.b, b.b);
    v.a = __hsub2(a.a, b.a); v.b = __hsub2(a.b, b.b);
    *(H4*)&xs[xi * 68 + rq] = u;
    *(H4*)&xs[(256 - xi) * 68 + rq] = v;
  }
  __syncthreads();
  const int r0 = (tid & 15) * 4;
  const int w0 = (tid >> 4) * 4;
  float ci_[4], si_[4], cp_[4], sp_[4], kk[4];
#pragma unroll
  for (int j = 0; j < 4; ++j) {
    float s, c;
    sincosf(W256 * (float)(w0 + j), &s, &c);
    kk[j] = 2.f * c;
    cp_[j] = 1.f; sp_[j] = 0.f;
    ci_[j] = c;  si_[j] = s;
  }
  float Cr[4][4], Ci[4][4];
  {  // edge terms: Re += X0 + (-1)^w X128
    H4 h0 = *(const H4*)&xs[r0];
    H4 h128 = *(const H4*)&xs[128 * 68 + r0];
    float x0f[4] = {__half2float(h0.a.x), __half2float(h0.a.y),
                    __half2float(h0.b.x), __half2float(h0.b.y)};
    float x1f[4] = {__half2float(h128.a.x), __half2float(h128.a.y),
                    __half2float(h128.b.x), __half2float(h128.b.y)};
#pragma unroll
    for (int j = 0; j < 4; ++j) {
      const float sg = (j & 1) ? -1.f : 1.f;
#pragma unroll
      for (int i = 0; i < 4; ++i) {
        Cr[j][i] = fmaf(sg, x1f[i], x0f[i]);
        Ci[j][i] = 0.f;
      }
    }
  }
  for (int xx = 1; xx < 128; ++xx) {
    H4 u = *(const H4*)&xs[xx * 68 + r0];
    H4 v = *(const H4*)&xs[(256 - xx) * 68 + r0];
    const float uf[4] = {__half2float(u.a.x), __half2float(u.a.y),
                         __half2float(u.b.x), __half2float(u.b.y)};
    const float vf[4] = {__half2float(v.a.x), __half2float(v.a.y),
                         __half2float(v.b.x), __half2float(v.b.y)};
#pragma unroll
    for (int j = 0; j < 4; ++j) {
      const float c = ci_[j], s = si_[j];
#pragma unroll
      for (int i = 0; i < 4; ++i) {
        Cr[j][i] = fmaf(uf[i], c, Cr[j][i]);
        Ci[j][i] = fmaf(-vf[i], s, Ci[j][i]);
      }
      const float cn = fmaf(kk[j], c, -cp_[j]);
      const float sn = fmaf(kk[j], s, -sp_[j]);
      cp_[j] = c; ci_[j] = cn;
      sp_[j] = s; si_[j] = sn;
    }
  }
#pragma unroll
  for (int i = 0; i < 4; ++i) {
    H8 o;
    o.a = __floats2half2_rn(Cr[0][i], Ci[0][i]);
    o.b = __floats2half2_rn(Cr[1][i], Ci[1][i]);
    o.c = __floats2half2_rn(Cr[2][i], Ci[2][i]);
    o.d = __floats2half2_rn(Cr[3][i], Ci[3][i]);
    z1h[(row0 + r0 + i) * 8 + (w0 >> 2)] = o;
  }
}

// kB: 1024 blocks = (bc, yq of 64 y) x 128 thr. Thread = (tg -> 4 t, wg -> 4 w).
__global__ __launch_bounds__(128) void kB(const H8* __restrict__ z1h,
                                          H8* __restrict__ z2p) {
  __shared__ __half zs[64 * 64];  // [y][w re/im], 8 KB
  const int bc = blockIdx.x >> 2, yq = blockIdx.x & 3;
  const int y0 = yq * 64;
  {
    const int4* src = (const int4*)(z1h + ((long)bc * 256 + y0) * 8);
    int4* dst = (int4*)zs;
    for (int i = threadIdx.x; i < 512; i += 128) dst[i] = src[i];
  }
  __syncthreads();
  const int t0 = (threadIdx.x & 15) * 4;
  const int w0 = (threadIdx.x >> 4) * 4;
  float ci_[4], si_[4], cp_[4], sp_[4], kk[4];
#pragma unroll
  for (int k = 0; k < 4; ++k) {
    const int t = t0 + k;
    const int h = (t < 32) ? t : (192 + t);
    const int m0 = (h * y0) & 255;
    const int mp = (h * (y0 + 255)) & 255;
    float s0, c0, sp1, cp1;
    sincosf(W256 * (float)m0, &s0, &c0);
    sincosf(W256 * (float)mp, &sp1, &cp1);
    ci_[k] = c0;  si_[k] = -s0;
    cp_[k] = cp1; sp_[k] = -sp1;
    kk[k] = 2.f * cosf(W256 * (float)h);
  }
  float ar[4][4], ai[4][4];
#pragma unroll
  for (int k = 0; k < 4; ++k)
#pragma unroll
    for (int i = 0; i < 4; ++i) { ar[k][i] = 0.f; ai[k][i] = 0.f; }
  for (int y = 0; y < 64; ++y) {
    H8 z = *(const H8*)&zs[y * 64 + w0 * 2];
    const float zr[4] = {__half2float(z.a.x), __half2float(z.b.x),
                         __half2float(z.c.x), __half2float(z.d.x)};
    const float zi[4] = {__half2float(z.a.y), __half2float(z.b.y),
                         __half2float(z.c.y), __half2float(z.d.y)};
#pragma unroll
    for (int k = 0; k < 4; ++k) {
      const float c = ci_[k], s = si_[k];
#pragma unroll
      for (int i = 0; i < 4; ++i) {
        ar[k][i] = fmaf(zr[i], c, fmaf(-zi[i], s, ar[k][i]));
        ai[k][i] = fmaf(zr[i], s, fmaf(zi[i], c, ai[k][i]));
      }
      const float cn = fmaf(kk[k], c, -cp_[k]);
      const float sn = fmaf(kk[k], s, -sp_[k]);
      cp_[k] = c; ci_[k] = cn;
      sp_[k] = s; si_[k] = sn;
    }
  }
#pragma unroll
  for (int k = 0; k < 4; ++k) {
    H8 o;
    o.a = __floats2half2_rn(ar[k][0], ai[k][0]);
    o.b = __floats2half2_rn(ar[k][1], ai[k][1]);
    o.c = __floats2half2_rn(ar[k][2], ai[k][2]);
    o.d = __floats2half2_rn(ar[k][3], ai[k][3]);
    z2p[(((long)yq * 256 + bc) * 64 + t0 + k) * 8 + (w0 >> 2)] = o;
  }
}

// kC: 1024 blocks x 256 thr; block = 16 modes (same b,t; 16 w). Sums 4 partials.
__global__ __launch_bounds__(256) void kC(const __half2* __restrict__ z2p,
                                          const float2* __restrict__ kp,
                                          __half2* __restrict__ g) {
  __shared__ float2 z2s[16 * 33];
  __shared__ float2 fk[16 * 33];
  __shared__ float2 tw[32];
  const int tid = threadIdx.x;
  if (tid < 32) {
    float s, c;
    sincosf(-TWO_PI * (float)tid / 32.0f, &s, &c);
    tw[tid] = make_float2(c, s);
  }
  const int m0 = blockIdx.x * 16;
  const int b = m0 >> 11;
  const int twi = m0 & 2047;
  const int t = twi >> 5;
  const int w0 = twi & 31;
  const int s_ = t >> 5, tm = t & 31;
  for (int i = tid; i < 512; i += 256) {
    const int ci = i >> 4, wj = i & 15;
    const long idx = ((long)(b * 32 + ci)) * 2048 + t * 32 + w0 + wj;
    float sr = 0.f, si = 0.f;
#pragma unroll
    for (int q = 0; q < 4; ++q) {
      const __half2 v = z2p[(long)q * 524288 + idx];
      sr += __half2float(v.x);
      si += __half2float(v.y);
    }
    z2s[wj * 33 + ci] = make_float2(sr, si);
  }
  __syncthreads();
  const int m = tid & 15;
  const int p = tid >> 4;
  const int cf0 = 2 * p, cf1 = 2 * p + 1;
  {
    float f0r = 0, f0i = 0, f1r = 0, f1i = 0;
    int i0 = 0, i1 = 0;
#pragma unroll 8
    for (int ci = 0; ci < 32; ++ci) {
      const float2 z = z2s[m * 33 + ci];
      const float2 t0 = tw[i0]; i0 = (i0 + cf0) & 31;
      const float2 t1 = tw[i1]; i1 = (i1 + cf1) & 31;
      f0r = fmaf(z.x, t0.x, fmaf(-z.y, t0.y, f0r));
      f0i = fmaf(z.x, t0.y, fmaf(z.y, t0.x, f0i));
      f1r = fmaf(z.x, t1.x, fmaf(-z.y, t1.y, f1r));
      f1i = fmaf(z.x, t1.y, fmaf(z.y, t1.x, f1i));
    }
    const float2 k0 = kp[((s_ * 32 + cf0) * 32 + tm) * 32 + w0 + m];
    const float2 k1 = kp[((s_ * 32 + cf1) * 32 + tm) * 32 + w0 + m];
    fk[m * 33 + cf0] = make_float2(f0r * k0.x - f0i * k0.y, f0r * k0.y + f0i * k0.x);
    fk[m * 33 + cf1] = make_float2(f1r * k1.x - f1i * k1.y, f1r * k1.y + f1i * k1.x);
  }
  __syncthreads();
  {
    float g0r = 0, g0i = 0, g1r = 0, g1i = 0;
    int i0 = 0, i1 = 0;
    const int co0 = 2 * p, co1 = 2 * p + 1;
#pragma unroll 8
    for (int cf = 0; cf < 32; ++cf) {
      const float2 f = fk[m * 33 + cf];
      const float2 t0 = tw[i0]; i0 = (i0 + co0) & 31;
      const float2 t1 = tw[i1]; i1 = (i1 + co1) & 31;
      g0r = fmaf(f.x, t0.x, fmaf(f.y, t0.y, g0r));
      g0i = fmaf(f.y, t0.x, fmaf(-f.x, t0.y, g0i));
      g1r = fmaf(f.x, t1.x, fmaf(f.y, t1.y, g1r));
      g1i = fmaf(f.y, t1.x, fmaf(-f.x, t1.y, g1i));
    }
    const float SC = 1.0f / 8192.0f;
    g[((long)(b * 32 + co0)) * 2048 + t * 32 + w0 + m] =
        __floats2half2_rn(g0r * SC, g0i * SC);
    g[((long)(b * 32 + co1)) * 2048 + t * 32 + w0 + m] =
        __floats2half2_rn(g1r * SC, g1i * SC);
  }
}

// kDE: 2048 blocks = (bc, yc of 32 y) x 256 thr, __launch_bounds__(256,4).
// Phase D: thread = (wg=tid&7 -> 4 w, yl=tid>>3 -> 1 y): Tr[4],Ti[4], 1 chain.
// Phase E: thread = (xg=tid&31 -> 4 x, rh=tid>>5 -> 4 contig rows): C[4][4],S[4][4].
__global__ __launch_bounds__(256, 4) void kDE(const __half2* __restrict__ g,
                                              float* __restrict__ out) {
  __shared__ __half2 gs[2048];     // [t][w], 8 KB
  __shared__ float2 Tst[32 * 33];  // [w][y], 8.25 KB
  const int tid = threadIdx.x;
  const int bc = blockIdx.x >> 3, yc = blockIdx.x & 7;
  const int y0 = yc * 32;
  {
    const int4* src = (const int4*)(g + (long)bc * 2048);
    int4* dst = (int4*)gs;
    for (int i = tid; i < 512; i += 256) dst[i] = src[i];
  }
  __syncthreads();
  // ---- Phase D ----
  {
    const int w0 = (tid & 7) * 4;
    const int yl = tid >> 3;
    const int y = y0 + yl;
    float sy, cy;
    sincosf(W256 * (float)y, &sy, &cy);
    const float kk = 2.f * cy;
    float ci_ = 1.f, si_ = 0.f;   // t=0
    float cp_ = cy, sp_ = -sy;    // t=-1: phase -y*W
    float Tr[4], Ti[4];
#pragma unroll
    for (int j = 0; j < 4; ++j) { Tr[j] = 0.f; Ti[j] = 0.f; }
    for (int t = 0; t < 32; ++t) {
      H8 gz = *(const H8*)&gs[t * 32 + w0];
      const float gr[4] = {__half2float(gz.a.x), __half2float(gz.b.x),
                           __half2float(gz.c.x), __half2float(gz.d.x)};
      const float gi[4] = {__half2float(gz.a.y), __half2float(gz.b.y),
                           __half2float(gz.c.y), __half2float(gz.d.y)};
      const float c = ci_, s = si_;
#pragma unroll
      for (int j = 0; j < 4; ++j) {
        Tr[j] = fmaf(gr[j], c, fmaf(-gi[j], s, Tr[j]));
        Ti[j] = fmaf(gr[j], s, fmaf(gi[j], c, Ti[j]));
      }
      const float cn = fmaf(kk, c, -cp_);
      const float sn = fmaf(kk, s, -sp_);
      cp_ = c; ci_ = cn;
      sp_ = s; si_ = sn;
    }
    {  // re-init for t=32: h = 224..255
      const int m32 = (224 * y) & 255, m31 = (223 * y) & 255;
      float s32, c32, s31, c31;
      sincosf(W256 * (float)m32, &s32, &c32);
      sincosf(W256 * (float)m31, &s31, &c31);
      ci_ = c32; si_ = s32;
      cp_ = c31; sp_ = s31;
    }
    for (int t = 32; t < 64; ++t) {
      H8 gz = *(const H8*)&gs[t * 32 + w0];
      const float gr[4] = {__half2float(gz.a.x), __half2float(gz.b.x),
                           __half2float(gz.c.x), __half2float(gz.d.x)};
      const float gi[4] = {__half2float(gz.a.y), __half2float(gz.b.y),
                           __half2float(gz.c.y), __half2float(gz.d.y)};
      const float c = ci_, s = si_;
#pragma unroll
      for (int j = 0; j < 4; ++j) {
        Tr[j] = fmaf(gr[j], c, fmaf(-gi[j], s, Tr[j]));
        Ti[j] = fmaf(gr[j], s, fmaf(gi[j], c, Ti[j]));
      }
      const float cn = fmaf(kk, c, -cp_);
      const float sn = fmaf(kk, s, -sp_);
      cp_ = c; ci_ = cn;
      sp_ = s; si_ = sn;
    }
#pragma unroll
    for (int j = 0; j < 4; ++j) {
      const float sc = (w0 + j == 0) ? (1.0f / 256.0f) : (2.0f / 256.0f);
      Tst[(w0 + j) * 33 + yl] = make_float2(Tr[j] * sc, Ti[j] * sc);
    }
  }
  __syncthreads();
  // ---- Phase E ----
  {
    const int xg = tid & 31, rh = tid >> 5;
    const int x0 = xg * 4;
    const int r0 = rh * 4;
    float ci_[4], si_[4], cp_[4], sp_[4], kk[4];
#pragma unroll
    for (int j = 0; j < 4; ++j) {
      float sx, cx;
      sincosf(W256 * (float)(x0 + j), &sx, &cx);
      kk[j] = 2.f * cx;
      ci_[j] = 1.f; si_[j] = 0.f;  // w=0
      cp_[j] = cx;  sp_[j] = -sx;  // w=-1
    }
    float C[4][4], S[4][4];
#pragma unroll
    for (int k = 0; k < 4; ++k)
#pragma unroll
      for (int j = 0; j < 4; ++j) { C[k][j] = 0.f; S[k][j] = 0.f; }
    for (int w = 0; w < 32; ++w) {
      float2 tv[4];
      *(float4*)&tv[0] = *(const float4*)&Tst[w * 33 + r0];
      *(float4*)&tv[2] = *(const float4*)&Tst[w * 33 + r0 + 2];
#pragma unroll
      for (int j = 0; j < 4; ++j) {
        const float c = ci_[j], s = si_[j];
#pragma unroll
        for (int k = 0; k < 4; ++k) {
          C[k][j] = fmaf(tv[k].x, c, C[k][j]);
          S[k][j] = fmaf(tv[k].y, s, S[k][j]);
        }
        const float cn = fmaf(kk[j], c, -cp_[j]);
        const float sn = fmaf(kk[j], s, -sp_[j]);
        cp_[j] = c; ci_[j] = cn;
        sp_[j] = s; si_[j] = sn;
      }
    }
    const long rowg0 = (long)bc * 256 + y0 + r0;
#pragma unroll
    for (int k = 0; k < 4; ++k) {
      float* base = out + (rowg0 + k) * 256;
      float4 d = make_float4(C[k][0] - S[k][0], C[k][1] - S[k][1],
                             C[k][2] - S[k][2], C[k][3] - S[k][3]);
      *(float4*)(base + x0) = d;
#pragma unroll
      for (int j = 0; j < 4; ++j)  // mirror (x=0 rewrites slot 0, same value)
        base[(256 - (x0 + j)) & 255] = C[k][j] + S[k][j];
    }
  }
  // column x=128: sum (-1)^w over scaled Tst
  if (tid < 32) {
    float se = 0.f, so = 0.f;
#pragma unroll
    for (int k = 0; k < 16; ++k) {
      se += Tst[(2 * k) * 33 + tid].x;
      so += Tst[(2 * k + 1) * 33 + tid].x;
    }
    out[((long)bc * 256 + y0 + tid) * 256 + 128] = se - so;
  }
}

extern "C" void kernel_launch(void* const* d_in, const int* in_sizes, int n_in,
                              void* d_out, int out_size, void* d_ws, size_t ws_size,
                              hipStream_t stream) {
  const float* x = (const float*)d_in[0];
  const float* kin = (const float*)d_in[1];
  const float* rp = (const float*)d_in[2];
  float* out = (float*)d_out;
  char* ws = (char*)d_ws;

  H8* z1h = (H8*)(ws);                            // 8 MB
  H8* z2p = (H8*)(ws + (8ull << 20));             // 8 MB
  __half2* g = (__half2*)(ws + (16ull << 20));    // 2 MB
  float2* kp = (float2*)(ws + (18ull << 20));     // 0.5 MB

  kP<<<256, 256, 0, stream>>>(kin, rp, kp);
  kA<<<1024, 128, 0, stream>>>(x, z1h);
  kB<<<1024, 128, 0, stream>>>(z1h, z2p);
  kC<<<1024, 256, 0, stream>>>((const __half2*)z2p, kp, g);
  kDE<<<2048, 256, 0, stream>>>(g, out);
}